// Round 6
// baseline (448.486 us; speedup 1.0000x reference)
//
#include <hip/hip_runtime.h>
#include <hip/hip_bf16.h>
#include <math.h>

#define EPB  32    // edges per block
#define MSTR 136   // m LDS row stride (shorts): 128 + 8 pad
#define FSTR 264   // node-kernel f stride

typedef __attribute__((ext_vector_type(8))) short short8;
typedef __attribute__((ext_vector_type(4))) float f32x4;

__device__ __forceinline__ unsigned short f2bf(float x) {
    unsigned int u = __float_as_uint(x);
    u += 0x7fffu + ((u >> 16) & 1u);   // round-to-nearest-even
    return (unsigned short)(u >> 16);
}
__device__ __forceinline__ float bf2f(short v) {
    return __uint_as_float(((unsigned int)(unsigned short)v) << 16);
}
__device__ __forceinline__ unsigned int pkbf(float a, float b) {
    __hip_bfloat162 h = __float22bfloat162_rn(make_float2(a, b));
    union { __hip_bfloat162 h2; unsigned int u; } cv; cv.h2 = h; return cv.u;
}
__device__ __forceinline__ float frcp(float x) { return __builtin_amdgcn_rcpf(x); }
__device__ __forceinline__ float fsilu(float x) {
    return x * frcp(1.0f + __expf(-x));
}
__device__ __forceinline__ float fsigm(float x) {
    return frcp(1.0f + __expf(-x));
}
__device__ __forceinline__ void atomAddF(float* p, float v) {
    unsafeAtomicAdd(p, v);   // hardware global_atomic_add_f32
}

// DPP tree-add over the 16 lanes of a DPP row, VALU-pipe only.
template<int CTRL>
__device__ __forceinline__ float dppAdd(float x) {
    int y = __builtin_amdgcn_update_dpp(0, __float_as_int(x), CTRL, 0xF, 0xF, false);
    return x + __int_as_float(y);
}
__device__ __forceinline__ float rowSum16(float g) {
    g = dppAdd<0xB1>(g);    // quad_perm [1,0,3,2]  (xor 1)
    g = dppAdd<0x4E>(g);    // quad_perm [2,3,0,1]  (xor 2)
    g = dppAdd<0x124>(g);   // row_ror:4
    g = dppAdd<0x128>(g);   // row_ror:8
    return g;
}

// ---------------------------------------------------------------------------
// Kernel A: weight transpose (fp32 [K][128] -> bf16 [128][K]) + dst histogram
//           + zero-fill of the hne/xne accumulators
// ---------------------------------------------------------------------------
struct PrepArgs { const float* src[10]; };

__global__ __launch_bounds__(256) void prep_hist_kernel(PrepArgs pa, short* __restrict__ wsb,
                                                        const int* __restrict__ lld,
                                                        const int* __restrict__ kld,
                                                        int* __restrict__ hist,
                                                        float* __restrict__ zfill) {
    int idx = blockIdx.x * 256 + threadIdx.x;
    if (idx < 245760) {
        int pair = idx / 49152;
        int rem  = idx - pair * 49152;
        int second = (rem >= 32768) ? 1 : 0;
        int mi = pair * 2 + second;
        int within = second ? (rem - 32768) : rem;
        int n, k, K;
        if (second) { K = 128; n = within >> 7; k = within & 127; }
        else        { K = 256; n = within >> 8; k = within & 255; }
        int dstoff = pair * 49152 + second * 32768;
        wsb[dstoff + n * K + k] = (short)f2bf(pa.src[mi][k * 128 + n]);
        return;
    }
    idx -= 245760;
    if (idx < 320000) { atomicAdd(&hist[lld[idx]], 1); return; }
    idx -= 320000;
    if (idx < 160000) { atomicAdd(&hist[10000 + kld[idx]], 1); return; }
    idx -= 160000;
    if (idx < 327500)  // 5,240,000 B of hne+xne, float4 strided
        ((float4*)zfill)[idx] = make_float4(0.f, 0.f, 0.f, 0.f);
}

// ---------------------------------------------------------------------------
// Kernel B: merged scan (blocks 0,1) + projection GEMMs (blocks 2..1257).
// ---------------------------------------------------------------------------
struct ProjDesc { const float* A; const short* Bt; short* out; const float* bias;
                  int rows; int ktb; int co; int hasb; };
struct BArgs {
    const int* hist;
    int* cursor;
    ProjDesc d[8];
};

__global__ __launch_bounds__(256) void scan_proj_kernel(BArgs ba) {
    __shared__ __align__(16) short a_lds[64 * MSTR];
    const int t = threadIdx.x;
    if (blockIdx.x < 2) {
        __shared__ int ps[256];
        const int* h = ba.hist + blockIdx.x * 10000;
        int* cur = ba.cursor + blockIdx.x * 10000;
        const int base = t * 40;
        int v[40];
#pragma unroll
        for (int i = 0; i < 40; i++) {
            int ii = base + i;
            v[i] = (ii < 10000) ? h[ii] : 0;
        }
        int s = 0;
#pragma unroll
        for (int i = 0; i < 40; i++) s += v[i];
        ps[t] = s;
        __syncthreads();
        for (int off = 1; off < 256; off <<= 1) {
            int x = (t >= off) ? ps[t - off] : 0;
            __syncthreads();
            ps[t] += x;
            __syncthreads();
        }
        int run = ps[t] - s;   // exclusive prefix of this chunk
#pragma unroll
        for (int i = 0; i < 40; i++) {
            int ii = base + i;
            if (ii < 10000) { cur[ii] = run; run += v[i]; }
        }
        return;
    }
    const int pb = blockIdx.x - 2;
    const int di = pb / 157, tile = pb - di * 157;
    const ProjDesc pd = ba.d[di];
    if (tile * 64 >= pd.rows) return;
    {
        const int r = t >> 2, q = t & 3;
        const int node = tile * 64 + r;
        short* arow = a_lds + r * MSTR + q * 32;
        if (node < pd.rows) {
            const float* ap = pd.A + (size_t)node * 128 + q * 32;
#pragma unroll
            for (int i = 0; i < 4; i++) {
                float4 v0 = *(const float4*)(ap + i * 8);
                float4 v1 = *(const float4*)(ap + i * 8 + 4);
                uint4 o;
                o.x = pkbf(v0.x, v0.y); o.y = pkbf(v0.z, v0.w);
                o.z = pkbf(v1.x, v1.y); o.w = pkbf(v1.z, v1.w);
                *(uint4*)(arow + i * 8) = o;
            }
        } else {
            uint4 z = make_uint4(0, 0, 0, 0);
#pragma unroll
            for (int i = 0; i < 4; i++) *(uint4*)(arow + i * 8) = z;
        }
    }
    __syncthreads();

    const int ln = t & 63, wv = t >> 6;
    const int lrow = ln & 15, quad = ln >> 4;
    const int c0 = wv * 32 + lrow, c1 = c0 + 16;

    short8 bf0[4], bf1[4];
#pragma unroll
    for (int kt = 0; kt < 4; kt++) {
        bf0[kt] = *(const short8*)(pd.Bt + c0 * 256 + (pd.ktb + kt) * 32 + quad * 8);
        bf1[kt] = *(const short8*)(pd.Bt + c1 * 256 + (pd.ktb + kt) * 32 + quad * 8);
    }
    const float bb0 = pd.hasb ? pd.bias[c0] : 0.0f;
    const float bb1 = pd.hasb ? pd.bias[c1] : 0.0f;
#pragma unroll
    for (int mt = 0; mt < 4; mt++) {
        short8 af[4];
#pragma unroll
        for (int kt = 0; kt < 4; kt++)
            af[kt] = *(const short8*)(&a_lds[(mt * 16 + lrow) * MSTR + kt * 32 + quad * 8]);
        f32x4 a0 = {0.f, 0.f, 0.f, 0.f}, a1 = {0.f, 0.f, 0.f, 0.f};
#pragma unroll
        for (int kt = 0; kt < 4; kt++) {
            a0 = __builtin_amdgcn_mfma_f32_16x16x32_bf16(af[kt], bf0[kt], a0, 0, 0, 0);
            a1 = __builtin_amdgcn_mfma_f32_16x16x32_bf16(af[kt], bf1[kt], a1, 0, 0, 0);
        }
#pragma unroll
        for (int r = 0; r < 4; r++) {
            const int node = tile * 64 + mt * 16 + quad * 4 + r;
            if (node < pd.rows) {
                pd.out[(size_t)node * 256 + pd.co + c0] = (short)f2bf(a0[r] + bb0);
                pd.out[(size_t)node * 256 + pd.co + c1] = (short)f2bf(a1[r] + bb1);
            }
        }
    }
}

// ---------------------------------------------------------------------------
// Kernel C: scatter only (counting-sort placement of packed (src,dst))
// ---------------------------------------------------------------------------
struct SArgs {
    const int *lls, *lld, *kls, *kld;
    int* cursor;
    int2 *ll_spk, *kl_spk;
};

__global__ __launch_bounds__(256) void scatter_kernel(SArgs sa) {
    int i = blockIdx.x * 256 + threadIdx.x;
    if (i < 320000) {
        int s = sa.lls[i];
        int d = sa.lld[i];
        int p = atomicAdd(&sa.cursor[d], 1);
        sa.ll_spk[p] = make_int2(s, d);
    } else if (i < 480000) {
        int j = i - 320000;
        int s = sa.kls[j];
        int d = sa.kld[j];
        int p = atomicAdd(&sa.cursor[10000 + d], 1);
        sa.kl_spk[p] = make_int2(s, d);
    }
}

// ---------------------------------------------------------------------------
// Edge kernel: EPB=32, 4 waves, 3 barriers, DPP gate reductions, XCD swizzle.
// Tail rework (r6): the old msg-overlay + 16-iteration serial segmented scan
// (~116 insts/thread) is replaced by direct atomics from the m2s registers
// with in-register run-merging over the dst-sorted 4-edge subgroups
// (~30 insts/thread, ~2x atomics).  B3 now only guards gate_l/sv_l.
// ---------------------------------------------------------------------------
struct EdgeSet {
    const short *Ps, *Pd;        // [nodes][256] bf16: 0..127 e-proj, 128..255 c-proj (b1 in Pd)
    const float *xs, *xd;
    const int2 *esd;             // dst-sorted packed (src,dst)
    const float *w256e, *w256c;  // dij coefficient rows (fp32)
    const short *W2t, *cW2t;     // [128][128] bf16 [col][k]
    const float *b2e, *b2c;
    const float *aW, *ab, *cW3;
};
struct EdgePair { EdgeSet s[2]; int split; };

__global__ __launch_bounds__(256, 6) void edge_kernel(EdgePair ep,
                                                      float* __restrict__ hne,
                                                      float* __restrict__ xne)
{
    __shared__ __align__(16) short mh[EPB * MSTR];
    __shared__ __align__(16) short mc[EPB * MSTR];
    __shared__ float sv_l[EPB];
    __shared__ float gate_l[EPB];
    __shared__ float xdf[3][EPB];
    __shared__ int   dstl[EPB];
    __shared__ float gpc[4][EPB];
    __shared__ float gpe[4][EPB];

    const int isKL = (blockIdx.x >= ep.split) ? 1 : 0;
    const EdgeSet P = ep.s[isKL];
    int b = blockIdx.x - (isKL ? ep.split : 0);
    // XCD swizzle: 10000 ll blocks = 8 x 1250, 5000 kl blocks = 8 x 625.
    const int nb8 = isKL ? 625 : 1250;
    b = (b & 7) * nb8 + (b >> 3);
    const int eb = b * EPB;
    const int t = threadIdx.x;

    // ---- phase 0: gather projections, fuse add+dij*w+silu, pack bf16 ----
    {
        const int e = t >> 3, q = t & 7;     // 8 threads/edge, 16 cols each
        const int eid = eb + e;
        const int2 sd = P.esd[eid];
        const int s = sd.x, d = sd.y;
        const short* psrow = P.Ps + (size_t)s * 256 + q * 16;
        const short* pdrow = P.Pd + (size_t)d * 256 + q * 16;
        // stage ALL scattered gathers first: 8 independent 16B loads in flight
        short8 ra[2][2], rb[2][2];
#pragma unroll
        for (int path = 0; path < 2; path++)
#pragma unroll
            for (int i = 0; i < 2; i++) {
                ra[path][i] = *(const short8*)(psrow + path * 128 + i * 8);
                rb[path][i] = *(const short8*)(pdrow + path * 128 + i * 8);
            }
        float dx = P.xs[s * 3 + 0] - P.xd[d * 3 + 0];
        float dy = P.xs[s * 3 + 1] - P.xd[d * 3 + 1];
        float dz = P.xs[s * 3 + 2] - P.xd[d * 3 + 2];
        float dd = __builtin_amdgcn_sqrtf(dx * dx + dy * dy + dz * dz);
        if (q == 0) {
            dstl[e] = d;
            float inv = frcp(dd + 1.0f);
            xdf[0][e] = dx * inv; xdf[1][e] = dy * inv; xdf[2][e] = dz * inv;
        }
#pragma unroll
        for (int path = 0; path < 2; path++) {
            const float* wq = (path ? P.w256c : P.w256e) + q * 16;
            short* mrow = (path ? mc : mh) + e * MSTR + q * 16;
#pragma unroll
            for (int i = 0; i < 2; i++) {
                short8 a = ra[path][i];
                short8 b2 = rb[path][i];
                float4 wA = *(const float4*)(wq + i * 8);
                float4 wB = *(const float4*)(wq + i * 8 + 4);
                float v0 = fsilu(bf2f(a[0]) + bf2f(b2[0]) + dd * wA.x);
                float v1 = fsilu(bf2f(a[1]) + bf2f(b2[1]) + dd * wA.y);
                float v2 = fsilu(bf2f(a[2]) + bf2f(b2[2]) + dd * wA.z);
                float v3 = fsilu(bf2f(a[3]) + bf2f(b2[3]) + dd * wA.w);
                float v4 = fsilu(bf2f(a[4]) + bf2f(b2[4]) + dd * wB.x);
                float v5 = fsilu(bf2f(a[5]) + bf2f(b2[5]) + dd * wB.y);
                float v6 = fsilu(bf2f(a[6]) + bf2f(b2[6]) + dd * wB.z);
                float v7 = fsilu(bf2f(a[7]) + bf2f(b2[7]) + dd * wB.w);
                uint4 o;
                o.x = pkbf(v0, v1); o.y = pkbf(v2, v3);
                o.z = pkbf(v4, v5); o.w = pkbf(v6, v7);
                *(uint4*)(mrow + i * 8) = o;
            }
        }
    }
    __syncthreads();   // B1

    const int ln = t & 63, wv = t >> 6;
    const int lrow = ln & 15, quad = ln >> 4;
    const int c0 = wv * 32 + lrow, c1 = c0 + 16;

    // ---- GEMM2c: c2 = silu(m_c @ cW2 + cb2); sv partials -> gpc ----
    {
        short8 bf0[4], bf1[4];
#pragma unroll
        for (int kt = 0; kt < 4; kt++) {
            bf0[kt] = *(const short8*)(P.cW2t + c0 * 128 + kt * 32 + quad * 8);
            bf1[kt] = *(const short8*)(P.cW2t + c1 * 128 + kt * 32 + quad * 8);
        }
        const float cw0 = P.cW3[c0], cw1 = P.cW3[c1];
        const float bb0 = P.b2c[c0], bb1 = P.b2c[c1];
#pragma unroll
        for (int mt = 0; mt < 2; mt++) {
            short8 af[4];
#pragma unroll
            for (int kt = 0; kt < 4; kt++)
                af[kt] = *(const short8*)(&mc[(mt * 16 + lrow) * MSTR + kt * 32 + quad * 8]);
            f32x4 a0 = {0.f, 0.f, 0.f, 0.f}, a1 = {0.f, 0.f, 0.f, 0.f};
#pragma unroll
            for (int kt = 0; kt < 4; kt++) {
                a0 = __builtin_amdgcn_mfma_f32_16x16x32_bf16(af[kt], bf0[kt], a0, 0, 0, 0);
                a1 = __builtin_amdgcn_mfma_f32_16x16x32_bf16(af[kt], bf1[kt], a1, 0, 0, 0);
            }
#pragma unroll
            for (int r = 0; r < 4; r++) {
                float v0 = fsilu(a0[r] + bb0);
                float v1 = fsilu(a1[r] + bb1);
                float g = rowSum16(v0 * cw0 + v1 * cw1);
                if (lrow == 0) gpc[wv][mt * 16 + quad * 4 + r] = g;
            }
        }
    }

    // ---- GEMM2e: m2 = silu(m_h @ eW2 + b2); gate partials -> gpe; m2 in regs ----
    float m2s[2][8];
    {
        short8 bf0[4], bf1[4];
#pragma unroll
        for (int kt = 0; kt < 4; kt++) {
            bf0[kt] = *(const short8*)(P.W2t + c0 * 128 + kt * 32 + quad * 8);
            bf1[kt] = *(const short8*)(P.W2t + c1 * 128 + kt * 32 + quad * 8);
        }
        const float aw0 = P.aW[c0], aw1 = P.aW[c1];
        const float bb0 = P.b2e[c0], bb1 = P.b2e[c1];
#pragma unroll
        for (int mt = 0; mt < 2; mt++) {
            short8 af[4];
#pragma unroll
            for (int kt = 0; kt < 4; kt++)
                af[kt] = *(const short8*)(&mh[(mt * 16 + lrow) * MSTR + kt * 32 + quad * 8]);
            f32x4 a0 = {0.f, 0.f, 0.f, 0.f}, a1 = {0.f, 0.f, 0.f, 0.f};
#pragma unroll
            for (int kt = 0; kt < 4; kt++) {
                a0 = __builtin_amdgcn_mfma_f32_16x16x32_bf16(af[kt], bf0[kt], a0, 0, 0, 0);
                a1 = __builtin_amdgcn_mfma_f32_16x16x32_bf16(af[kt], bf1[kt], a1, 0, 0, 0);
            }
#pragma unroll
            for (int r = 0; r < 4; r++) {
                float v0 = fsilu(a0[r] + bb0);
                float v1 = fsilu(a1[r] + bb1);
                m2s[mt][r] = v0; m2s[mt][4 + r] = v1;
                float g = rowSum16(v0 * aw0 + v1 * aw1);
                if (lrow == 0) gpe[wv][mt * 16 + quad * 4 + r] = g;
            }
        }
    }
    __syncthreads();   // B2 (gpc/gpe complete)

    if (t < EPB) {
        sv_l[t]   = gpc[0][t] + gpc[1][t] + gpc[2][t] + gpc[3][t];
        gate_l[t] = fsigm(gpe[0][t] + gpe[1][t] + gpe[2][t] + gpe[3][t] + P.ab[0]);
    }
    __syncthreads();   // B3 (guards gate_l/sv_l only)

    // ---- h-path: direct atomics from registers, in-register run merge ----
#pragma unroll
    for (int mt = 0; mt < 2; mt++) {
        const int e0 = mt * 16 + quad * 4;
        float a0 = m2s[mt][0] * gate_l[e0];
        float a1 = m2s[mt][4] * gate_l[e0];
        int cur = dstl[e0];
#pragma unroll
        for (int r = 1; r < 4; r++) {
            const int e = e0 + r;
            const int d = dstl[e];
            const float g = gate_l[e];
            if (d != cur) {
                atomAddF(&hne[(size_t)cur * 128 + c0], a0);
                atomAddF(&hne[(size_t)cur * 128 + c1], a1);
                a0 = 0.0f; a1 = 0.0f; cur = d;
            }
            a0 += m2s[mt][r] * g;
            a1 += m2s[mt][4 + r] * g;
        }
        atomAddF(&hne[(size_t)cur * 128 + c0], a0);
        atomAddF(&hne[(size_t)cur * 128 + c1], a1);
    }
    // ---- x-path: 6 threads, 2-way split serial scan ----
    if (t < 6) {
        const int ax = (t >= 3) ? (t - 3) : t;
        const int e0 = (t >= 3) ? 16 : 0;
        float acc = 0.0f;
        int cur = dstl[e0];
        for (int e = e0; e < e0 + 16; e++) {
            const int d = dstl[e];
            if (d != cur) {
                atomAddF(&xne[cur * 3 + ax], acc);
                acc = 0.0f; cur = d;
            }
            acc += sv_l[e] * xdf[ax][e];
        }
        atomAddF(&xne[cur * 3 + ax], acc);
    }
}

// ---------------------------------------------------------------------------
// Node kernel: reads WS accumulators, writes d_out exactly once per element.
// ---------------------------------------------------------------------------
__global__ __launch_bounds__(256) void node_kernel(
    const float* __restrict__ h_lig, const float* __restrict__ zlig,
    const short* __restrict__ W1t, const float* __restrict__ b1v,
    const short* __restrict__ W2t, const float* __restrict__ b2v,
    const float* __restrict__ x_lig,
    const float* __restrict__ acc_h, const float* __restrict__ acc_x,
    float* __restrict__ h_out, float* __restrict__ x_out)
{
    __shared__ __align__(16) short f_lds[64 * FSTR];
    __shared__ __align__(16) short m_lds[64 * MSTR];
    const int t = threadIdx.x;
    const int nb = blockIdx.x * 64;

    {
        const int e = t >> 2, q = t & 3;
        const int node = nb + e;
        short* frow = &f_lds[e * FSTR + q * 32];
        if (node < 10000) {
            const float zi = frcp(zlig[node]);
            const float4* hp = (const float4*)(h_lig + (size_t)node * 128 + q * 32);
            const float4* np = (const float4*)(acc_h + (size_t)node * 128 + q * 32);
#pragma unroll
            for (int i = 0; i < 8; i++) {
                float4 v = hp[i];
                *(uint2*)(frow + i * 4) = make_uint2(pkbf(v.x, v.y), pkbf(v.z, v.w));
            }
#pragma unroll
            for (int i = 0; i < 8; i++) {
                float4 v = np[i];
                *(uint2*)(frow + 128 + i * 4) =
                    make_uint2(pkbf(v.x * zi, v.y * zi), pkbf(v.z * zi, v.w * zi));
            }
        } else {
            const uint2 zz = make_uint2(0, 0);
#pragma unroll
            for (int i = 0; i < 8; i++) {
                *(uint2*)(frow + i * 4) = zz;
                *(uint2*)(frow + 128 + i * 4) = zz;
            }
        }
    }
    __syncthreads();

    const int ln = t & 63, wv = t >> 6;
    const int lrow = ln & 15, quad = ln >> 4;
    const int c0 = wv * 32 + lrow, c1 = c0 + 16;

    {
        short8 bf0[8], bf1[8];
#pragma unroll
        for (int kt = 0; kt < 8; kt++) {
            bf0[kt] = *(const short8*)(W1t + c0 * 256 + kt * 32 + quad * 8);
            bf1[kt] = *(const short8*)(W1t + c1 * 256 + kt * 32 + quad * 8);
        }
        const float bb0 = b1v[c0], bb1 = b1v[c1];
#pragma unroll
        for (int mt = 0; mt < 4; mt++) {
            short8 af[8];
#pragma unroll
            for (int kt = 0; kt < 8; kt++)
                af[kt] = *(const short8*)(&f_lds[(mt * 16 + lrow) * FSTR + kt * 32 + quad * 8]);
            f32x4 a0 = {0.f, 0.f, 0.f, 0.f}, a1 = {0.f, 0.f, 0.f, 0.f};
#pragma unroll
            for (int kt = 0; kt < 8; kt++) {
                a0 = __builtin_amdgcn_mfma_f32_16x16x32_bf16(af[kt], bf0[kt], a0, 0, 0, 0);
                a1 = __builtin_amdgcn_mfma_f32_16x16x32_bf16(af[kt], bf1[kt], a1, 0, 0, 0);
            }
#pragma unroll
            for (int r = 0; r < 4; r++) {
                const int erow = mt * 16 + quad * 4 + r;
                m_lds[erow * MSTR + c0] = (short)f2bf(fsilu(a0[r] + bb0));
                m_lds[erow * MSTR + c1] = (short)f2bf(fsilu(a1[r] + bb1));
            }
        }
    }
    __syncthreads();

    {
        short8 bf0[4], bf1[4];
#pragma unroll
        for (int kt = 0; kt < 4; kt++) {
            bf0[kt] = *(const short8*)(W2t + c0 * 128 + kt * 32 + quad * 8);
            bf1[kt] = *(const short8*)(W2t + c1 * 128 + kt * 32 + quad * 8);
        }
        const float bb0 = b2v[c0], bb1 = b2v[c1];
#pragma unroll
        for (int mt = 0; mt < 4; mt++) {
            short8 af[4];
#pragma unroll
            for (int kt = 0; kt < 4; kt++)
                af[kt] = *(const short8*)(&m_lds[(mt * 16 + lrow) * MSTR + kt * 32 + quad * 8]);
            f32x4 a0 = {0.f, 0.f, 0.f, 0.f}, a1 = {0.f, 0.f, 0.f, 0.f};
#pragma unroll
            for (int kt = 0; kt < 4; kt++) {
                a0 = __builtin_amdgcn_mfma_f32_16x16x32_bf16(af[kt], bf0[kt], a0, 0, 0, 0);
                a1 = __builtin_amdgcn_mfma_f32_16x16x32_bf16(af[kt], bf1[kt], a1, 0, 0, 0);
            }
#pragma unroll
            for (int r = 0; r < 4; r++) {
                const int node = nb + mt * 16 + quad * 4 + r;
                if (node < 10000) {
                    h_out[(size_t)node * 128 + c0] = a0[r] + bb0 + h_lig[(size_t)node * 128 + c0];
                    h_out[(size_t)node * 128 + c1] = a1[r] + bb1 + h_lig[(size_t)node * 128 + c1];
                }
            }
        }
    }
    if (t < 64) {
        const int node = nb + t;
        if (node < 10000) {
            const float zi = frcp(zlig[node]);
#pragma unroll
            for (int i = 0; i < 3; i++)
                x_out[node * 3 + i] = x_lig[node * 3 + i] + acc_x[node * 3 + i] * zi;
        }
    }
}

extern "C" void kernel_launch(void* const* d_in, const int* in_sizes, int n_in,
                              void* d_out, int out_size, void* d_ws, size_t ws_size,
                              hipStream_t stream)
{
    (void)in_sizes; (void)n_in; (void)ws_size; (void)out_size;
    const float* h_lig  = (const float*)d_in[0];
    const float* h_kp   = (const float*)d_in[1];
    const float* x_lig  = (const float*)d_in[2];
    const float* x_kp   = (const float*)d_in[3];
    const float* z_lig  = (const float*)d_in[4];
    const float* ll_eW1 = (const float*)d_in[5];
    const float* ll_eb1 = (const float*)d_in[6];
    const float* ll_eW2 = (const float*)d_in[7];
    const float* ll_eb2 = (const float*)d_in[8];
    const float* ll_aW  = (const float*)d_in[9];
    const float* ll_ab  = (const float*)d_in[10];
    const float* ll_cW1 = (const float*)d_in[11];
    const float* ll_cb1 = (const float*)d_in[12];
    const float* ll_cW2 = (const float*)d_in[13];
    const float* ll_cb2 = (const float*)d_in[14];
    const float* ll_cW3 = (const float*)d_in[15];
    const float* kl_eW1 = (const float*)d_in[16];
    const float* kl_eb1 = (const float*)d_in[17];
    const float* kl_eW2 = (const float*)d_in[18];
    const float* kl_eb2 = (const float*)d_in[19];
    const float* kl_aW  = (const float*)d_in[20];
    const float* kl_ab  = (const float*)d_in[21];
    const float* kl_cW1 = (const float*)d_in[22];
    const float* kl_cb1 = (const float*)d_in[23];
    const float* kl_cW2 = (const float*)d_in[24];
    const float* kl_cb2 = (const float*)d_in[25];
    const float* kl_cW3 = (const float*)d_in[26];
    const float* n_W1   = (const float*)d_in[27];
    const float* n_b1   = (const float*)d_in[28];
    const float* n_W2   = (const float*)d_in[29];
    const float* n_b2   = (const float*)d_in[30];
    const int* ll_src = (const int*)d_in[31];
    const int* ll_dst = (const int*)d_in[32];
    const int* kl_src = (const int*)d_in[33];
    const int* kl_dst = (const int*)d_in[34];

    float* h_out = (float*)d_out;            // [10000,128]
    float* x_out = h_out + 1280000;          // [10000,3]

    // ws layout (bytes) — ~26.1 MB; accumulators live in WS (d_out write-once)
    char* wsc = (char*)d_ws;
    short* wsb    = (short*)wsc;                 //       0: weights (491,520 B)
    short* P_ll_s = (short*)(wsc +   491520);    // 5,120,000 B  [10000][256]
    short* P_ll_d = (short*)(wsc +  5611520);    // 5,120,000 B
    short* P_kl_s = (short*)(wsc + 10731520);    // 1,024,000 B  [2000][256]
    short* P_kl_d = (short*)(wsc + 11755520);    // 5,120,000 B
    int2* ll_spk  = (int2*)(wsc + 16875520);     // 2,560,000 B  packed (src,dst)
    int2* kl_spk  = (int2*)(wsc + 19435520);     // 1,280,000 B
    int* hist     = (int*)(wsc + 20715520);      //    80,000 B (20000 ints)
    int* cursor   = (int*)(wsc + 20795520);      //    80,000 B
    float* hne    = (float*)(wsc + 20875520);    // 5,120,000 B  [10000][128]
    float* xne    = (float*)(wsc + 25995520);    //   120,000 B  [10000][3] -> end 26,115,520

    (void)hipMemsetAsync(hist, 0, 80000, stream);

    // A. weight transpose + histogram + hne/xne zero-fill
    {
        PrepArgs pa;
        pa.src[0] = ll_eW1; pa.src[1] = ll_eW2; pa.src[2] = ll_cW1; pa.src[3] = ll_cW2;
        pa.src[4] = kl_eW1; pa.src[5] = kl_eW2; pa.src[6] = kl_cW1; pa.src[7] = kl_cW2;
        pa.src[8] = n_W1;   pa.src[9] = n_W2;
        prep_hist_kernel<<<4115, 256, 0, stream>>>(pa, wsb, ll_dst, kl_dst, hist, hne);
    }
    // B. scan (2 blocks) overlapped with projection GEMMs (1256 blocks)
    {
        BArgs ba;
        ba.hist = hist; ba.cursor = cursor;
        ba.d[0] = { h_lig, wsb + 0,      P_ll_s, ll_eb1, 10000, 0, 0,   0 };
        ba.d[1] = { h_lig, wsb + 49152,  P_ll_s, ll_cb1, 10000, 0, 128, 0 };
        ba.d[2] = { h_lig, wsb + 0,      P_ll_d, ll_eb1, 10000, 4, 0,   1 };
        ba.d[3] = { h_lig, wsb + 49152,  P_ll_d, ll_cb1, 10000, 4, 128, 1 };
        ba.d[4] = { h_kp,  wsb + 98304,  P_kl_s, kl_eb1,  2000, 0, 0,   0 };
        ba.d[5] = { h_kp,  wsb + 147456, P_kl_s, kl_cb1,  2000, 0, 128, 0 };
        ba.d[6] = { h_lig, wsb + 98304,  P_kl_d, kl_eb1, 10000, 4, 0,   1 };
        ba.d[7] = { h_lig, wsb + 147456, P_kl_d, kl_cb1, 10000, 4, 128, 1 };
        scan_proj_kernel<<<2 + 8 * 157, 256, 0, stream>>>(ba);
    }
    // C. scatter
    {
        SArgs sa;
        sa.lls = ll_src; sa.lld = ll_dst; sa.kls = kl_src; sa.kld = kl_dst;
        sa.cursor = cursor;
        sa.ll_spk = ll_spk; sa.kl_spk = kl_spk;
        scatter_kernel<<<1875, 256, 0, stream>>>(sa);
    }
    // D. edges (ll + kl in one launch), EPB=32, XCD-swizzled
    {
        EdgePair ep;
        ep.split = 10000;
        ep.s[0] = { P_ll_s, P_ll_d, x_lig, x_lig, ll_spk,
                    ll_eW1 + 256 * 128, ll_cW1 + 256 * 128,
                    wsb + 32768, wsb + 81920, ll_eb2, ll_cb2,
                    ll_aW, ll_ab, ll_cW3 };
        ep.s[1] = { P_kl_s, P_kl_d, x_kp, x_lig, kl_spk,
                    kl_eW1 + 256 * 128, kl_cW1 + 256 * 128,
                    wsb + 131072, wsb + 180224, kl_eb2, kl_cb2,
                    kl_aW, kl_ab, kl_cW3 };
        edge_kernel<<<15000, 256, 0, stream>>>(ep, hne, xne);
    }
    // E. node MLP -> final outputs into d_out (write-once)
    node_kernel<<<157, 256, 0, stream>>>(
        h_lig, z_lig, wsb + 196608, n_b1, wsb + 229376, n_b2,
        x_lig, hne, xne, h_out, x_out);
}

// Round 7
// 370.981 us; speedup vs baseline: 1.2089x; 1.2089x over previous
//
#include <hip/hip_runtime.h>
#include <hip/hip_bf16.h>
#include <math.h>

#define EPB  32    // edges per block
#define MSTR 136   // m LDS row stride (shorts): 128 + 8 pad
#define FSTR 264   // node-kernel f stride

typedef __attribute__((ext_vector_type(8))) short short8;
typedef __attribute__((ext_vector_type(4))) float f32x4;

__device__ __forceinline__ unsigned short f2bf(float x) {
    unsigned int u = __float_as_uint(x);
    u += 0x7fffu + ((u >> 16) & 1u);   // round-to-nearest-even
    return (unsigned short)(u >> 16);
}
__device__ __forceinline__ float bf2f(short v) {
    return __uint_as_float(((unsigned int)(unsigned short)v) << 16);
}
__device__ __forceinline__ unsigned int pkbf(float a, float b) {
    __hip_bfloat162 h = __float22bfloat162_rn(make_float2(a, b));
    union { __hip_bfloat162 h2; unsigned int u; } cv; cv.h2 = h; return cv.u;
}
__device__ __forceinline__ float frcp(float x) { return __builtin_amdgcn_rcpf(x); }
__device__ __forceinline__ float fsilu(float x) {
    return x * frcp(1.0f + __expf(-x));
}
__device__ __forceinline__ float fsigm(float x) {
    return frcp(1.0f + __expf(-x));
}
__device__ __forceinline__ void atomAddF(float* p, float v) {
    unsafeAtomicAdd(p, v);   // hardware global_atomic_add_f32
}

// DPP tree-add over the 16 lanes of a DPP row, VALU-pipe only.
template<int CTRL>
__device__ __forceinline__ float dppAdd(float x) {
    int y = __builtin_amdgcn_update_dpp(0, __float_as_int(x), CTRL, 0xF, 0xF, false);
    return x + __int_as_float(y);
}
__device__ __forceinline__ float rowSum16(float g) {
    g = dppAdd<0xB1>(g);    // quad_perm [1,0,3,2]  (xor 1)
    g = dppAdd<0x4E>(g);    // quad_perm [2,3,0,1]  (xor 2)
    g = dppAdd<0x124>(g);   // row_ror:4
    g = dppAdd<0x128>(g);   // row_ror:8
    return g;
}

// ---------------------------------------------------------------------------
// Kernel A: weight transpose (fp32 [K][128] -> bf16 [128][K]) + dst histogram
//           + zero-fill of the hne/xne accumulators
// ---------------------------------------------------------------------------
struct PrepArgs { const float* src[10]; };

__global__ __launch_bounds__(256) void prep_hist_kernel(PrepArgs pa, short* __restrict__ wsb,
                                                        const int* __restrict__ lld,
                                                        const int* __restrict__ kld,
                                                        int* __restrict__ hist,
                                                        float* __restrict__ zfill) {
    int idx = blockIdx.x * 256 + threadIdx.x;
    if (idx < 245760) {
        int pair = idx / 49152;
        int rem  = idx - pair * 49152;
        int second = (rem >= 32768) ? 1 : 0;
        int mi = pair * 2 + second;
        int within = second ? (rem - 32768) : rem;
        int n, k, K;
        if (second) { K = 128; n = within >> 7; k = within & 127; }
        else        { K = 256; n = within >> 8; k = within & 255; }
        int dstoff = pair * 49152 + second * 32768;
        wsb[dstoff + n * K + k] = (short)f2bf(pa.src[mi][k * 128 + n]);
        return;
    }
    idx -= 245760;
    if (idx < 320000) { atomicAdd(&hist[lld[idx]], 1); return; }
    idx -= 320000;
    if (idx < 160000) { atomicAdd(&hist[10000 + kld[idx]], 1); return; }
    idx -= 160000;
    if (idx < 327500)  // 5,240,000 B of hne+xne, float4 strided
        ((float4*)zfill)[idx] = make_float4(0.f, 0.f, 0.f, 0.f);
}

// ---------------------------------------------------------------------------
// Kernel B: merged scan (blocks 0,1) + PAIRED projection GEMMs (blocks 2..629).
// Each pair shares the A-tile and the [rows][256] output (co=0 and co=128):
// one LDS stage feeds both GEMMs -> half the A traffic, contiguous stores.
// ---------------------------------------------------------------------------
struct ProjPair { const float* A; const short* Bt0; const short* Bt1; short* out;
                  const float* b0; const float* b1; int rows; int ktb; int hasb; };
struct BArgs {
    const int* hist;
    int* cursor;
    ProjPair p[4];
};

__global__ __launch_bounds__(256) void scan_proj_kernel(BArgs ba) {
    __shared__ __align__(16) short a_lds[64 * MSTR];
    const int t = threadIdx.x;
    if (blockIdx.x < 2) {
        __shared__ int ps[256];
        const int* h = ba.hist + blockIdx.x * 10000;
        int* cur = ba.cursor + blockIdx.x * 10000;
        const int base = t * 40;
        int v[40];
#pragma unroll
        for (int i = 0; i < 40; i++) {
            int ii = base + i;
            v[i] = (ii < 10000) ? h[ii] : 0;
        }
        int s = 0;
#pragma unroll
        for (int i = 0; i < 40; i++) s += v[i];
        ps[t] = s;
        __syncthreads();
        for (int off = 1; off < 256; off <<= 1) {
            int x = (t >= off) ? ps[t - off] : 0;
            __syncthreads();
            ps[t] += x;
            __syncthreads();
        }
        int run = ps[t] - s;   // exclusive prefix of this chunk
#pragma unroll
        for (int i = 0; i < 40; i++) {
            int ii = base + i;
            if (ii < 10000) { cur[ii] = run; run += v[i]; }
        }
        return;
    }
    const int pb = blockIdx.x - 2;
    const int pi = pb / 157, tile = pb - pi * 157;
    const ProjPair pd = ba.p[pi];
    if (tile * 64 >= pd.rows) return;
    {
        const int r = t >> 2, q = t & 3;
        const int node = tile * 64 + r;
        short* arow = a_lds + r * MSTR + q * 32;
        if (node < pd.rows) {
            const float* ap = pd.A + (size_t)node * 128 + q * 32;
#pragma unroll
            for (int i = 0; i < 4; i++) {
                float4 v0 = *(const float4*)(ap + i * 8);
                float4 v1 = *(const float4*)(ap + i * 8 + 4);
                uint4 o;
                o.x = pkbf(v0.x, v0.y); o.y = pkbf(v0.z, v0.w);
                o.z = pkbf(v1.x, v1.y); o.w = pkbf(v1.z, v1.w);
                *(uint4*)(arow + i * 8) = o;
            }
        } else {
            uint4 z = make_uint4(0, 0, 0, 0);
#pragma unroll
            for (int i = 0; i < 4; i++) *(uint4*)(arow + i * 8) = z;
        }
    }
    __syncthreads();

    const int ln = t & 63, wv = t >> 6;
    const int lrow = ln & 15, quad = ln >> 4;
    const int c0 = wv * 32 + lrow, c1 = c0 + 16;

#pragma unroll
    for (int g = 0; g < 2; g++) {
        const short* Bt = g ? pd.Bt1 : pd.Bt0;
        const float* bias = g ? pd.b1 : pd.b0;
        const int co = g * 128;
        short8 bf0[4], bf1[4];
#pragma unroll
        for (int kt = 0; kt < 4; kt++) {
            bf0[kt] = *(const short8*)(Bt + c0 * 256 + (pd.ktb + kt) * 32 + quad * 8);
            bf1[kt] = *(const short8*)(Bt + c1 * 256 + (pd.ktb + kt) * 32 + quad * 8);
        }
        const float bb0 = pd.hasb ? bias[c0] : 0.0f;
        const float bb1 = pd.hasb ? bias[c1] : 0.0f;
#pragma unroll
        for (int mt = 0; mt < 4; mt++) {
            short8 af[4];
#pragma unroll
            for (int kt = 0; kt < 4; kt++)
                af[kt] = *(const short8*)(&a_lds[(mt * 16 + lrow) * MSTR + kt * 32 + quad * 8]);
            f32x4 a0 = {0.f, 0.f, 0.f, 0.f}, a1 = {0.f, 0.f, 0.f, 0.f};
#pragma unroll
            for (int kt = 0; kt < 4; kt++) {
                a0 = __builtin_amdgcn_mfma_f32_16x16x32_bf16(af[kt], bf0[kt], a0, 0, 0, 0);
                a1 = __builtin_amdgcn_mfma_f32_16x16x32_bf16(af[kt], bf1[kt], a1, 0, 0, 0);
            }
#pragma unroll
            for (int r = 0; r < 4; r++) {
                const int node = tile * 64 + mt * 16 + quad * 4 + r;
                if (node < pd.rows) {
                    pd.out[(size_t)node * 256 + co + c0] = (short)f2bf(a0[r] + bb0);
                    pd.out[(size_t)node * 256 + co + c1] = (short)f2bf(a1[r] + bb1);
                }
            }
        }
    }
}

// ---------------------------------------------------------------------------
// Kernel C: scatter only (counting-sort placement of packed (src,dst))
// ---------------------------------------------------------------------------
struct SArgs {
    const int *lls, *lld, *kls, *kld;
    int* cursor;
    int2 *ll_spk, *kl_spk;
};

__global__ __launch_bounds__(256) void scatter_kernel(SArgs sa) {
    int i = blockIdx.x * 256 + threadIdx.x;
    if (i < 320000) {
        int s = sa.lls[i];
        int d = sa.lld[i];
        int p = atomicAdd(&sa.cursor[d], 1);
        sa.ll_spk[p] = make_int2(s, d);
    } else if (i < 480000) {
        int j = i - 320000;
        int s = sa.kls[j];
        int d = sa.kld[j];
        int p = atomicAdd(&sa.cursor[10000 + d], 1);
        sa.kl_spk[p] = make_int2(s, d);
    }
}

// ---------------------------------------------------------------------------
// Edge kernel: round-4 proven version (180.1 us).  EPB=32, 4 waves, 3
// barriers, DPP gate reductions, msg-overlay + LDS segmented scan tail
// (r6 showed direct-atomic tail quadruples WRITE_SIZE and costs +65 us).
// ---------------------------------------------------------------------------
struct EdgeSet {
    const short *Ps, *Pd;        // [nodes][256] bf16: 0..127 e-proj, 128..255 c-proj (b1 in Pd)
    const float *xs, *xd;
    const int2 *esd;             // dst-sorted packed (src,dst)
    const float *w256e, *w256c;  // dij coefficient rows (fp32)
    const short *W2t, *cW2t;     // [128][128] bf16 [col][k]
    const float *b2e, *b2c;
    const float *aW, *ab, *cW3;
};
struct EdgePair { EdgeSet s[2]; int split; };

__global__ __launch_bounds__(256, 6) void edge_kernel(EdgePair ep,
                                                      float* __restrict__ hne,
                                                      float* __restrict__ xne)
{
    __shared__ __align__(16) char mbuf[EPB * MSTR * 4];  // 17408: mh|mc bf16, overlay msg f32
    __shared__ float sv_l[EPB];
    __shared__ float gate_l[EPB];
    __shared__ float xdf[3][EPB];
    __shared__ int   dstl[EPB];
    __shared__ float gpc[4][EPB];
    __shared__ float gpe[4][EPB];

    short* mh = (short*)mbuf;
    short* mc = (short*)(mbuf + EPB * MSTR * 2);
    float* msg = (float*)mbuf;          // stride 132 floats, overlays mh+mc after GEMMs

    const int isKL = (blockIdx.x >= ep.split) ? 1 : 0;
    const EdgeSet P = ep.s[isKL];
    int b = blockIdx.x - (isKL ? ep.split : 0);
    // XCD swizzle: 10000 ll blocks = 8 x 1250, 5000 kl blocks = 8 x 625.
    const int nb8 = isKL ? 625 : 1250;
    b = (b & 7) * nb8 + (b >> 3);
    const int eb = b * EPB;
    const int t = threadIdx.x;

    // ---- phase 0: gather projections, fuse add+dij*w+silu, pack bf16 ----
    {
        const int e = t >> 3, q = t & 7;     // 8 threads/edge, 16 cols each
        const int eid = eb + e;
        const int2 sd = P.esd[eid];
        const int s = sd.x, d = sd.y;
        const short* psrow = P.Ps + (size_t)s * 256 + q * 16;
        const short* pdrow = P.Pd + (size_t)d * 256 + q * 16;
        // stage ALL scattered gathers first: 8 independent 16B loads in flight
        short8 ra[2][2], rb[2][2];
#pragma unroll
        for (int path = 0; path < 2; path++)
#pragma unroll
            for (int i = 0; i < 2; i++) {
                ra[path][i] = *(const short8*)(psrow + path * 128 + i * 8);
                rb[path][i] = *(const short8*)(pdrow + path * 128 + i * 8);
            }
        float dx = P.xs[s * 3 + 0] - P.xd[d * 3 + 0];
        float dy = P.xs[s * 3 + 1] - P.xd[d * 3 + 1];
        float dz = P.xs[s * 3 + 2] - P.xd[d * 3 + 2];
        float dd = __builtin_amdgcn_sqrtf(dx * dx + dy * dy + dz * dz);
        if (q == 0) {
            dstl[e] = d;
            float inv = frcp(dd + 1.0f);
            xdf[0][e] = dx * inv; xdf[1][e] = dy * inv; xdf[2][e] = dz * inv;
        }
#pragma unroll
        for (int path = 0; path < 2; path++) {
            const float* wq = (path ? P.w256c : P.w256e) + q * 16;
            short* mrow = (path ? mc : mh) + e * MSTR + q * 16;
#pragma unroll
            for (int i = 0; i < 2; i++) {
                short8 a = ra[path][i];
                short8 b2 = rb[path][i];
                float4 wA = *(const float4*)(wq + i * 8);
                float4 wB = *(const float4*)(wq + i * 8 + 4);
                float v0 = fsilu(bf2f(a[0]) + bf2f(b2[0]) + dd * wA.x);
                float v1 = fsilu(bf2f(a[1]) + bf2f(b2[1]) + dd * wA.y);
                float v2 = fsilu(bf2f(a[2]) + bf2f(b2[2]) + dd * wA.z);
                float v3 = fsilu(bf2f(a[3]) + bf2f(b2[3]) + dd * wA.w);
                float v4 = fsilu(bf2f(a[4]) + bf2f(b2[4]) + dd * wB.x);
                float v5 = fsilu(bf2f(a[5]) + bf2f(b2[5]) + dd * wB.y);
                float v6 = fsilu(bf2f(a[6]) + bf2f(b2[6]) + dd * wB.z);
                float v7 = fsilu(bf2f(a[7]) + bf2f(b2[7]) + dd * wB.w);
                uint4 o;
                o.x = pkbf(v0, v1); o.y = pkbf(v2, v3);
                o.z = pkbf(v4, v5); o.w = pkbf(v6, v7);
                *(uint4*)(mrow + i * 8) = o;
            }
        }
    }
    __syncthreads();   // B1

    const int ln = t & 63, wv = t >> 6;
    const int lrow = ln & 15, quad = ln >> 4;
    const int c0 = wv * 32 + lrow, c1 = c0 + 16;

    // ---- GEMM2c: c2 = silu(m_c @ cW2 + cb2); sv partials -> gpc ----
    {
        short8 bf0[4], bf1[4];
#pragma unroll
        for (int kt = 0; kt < 4; kt++) {
            bf0[kt] = *(const short8*)(P.cW2t + c0 * 128 + kt * 32 + quad * 8);
            bf1[kt] = *(const short8*)(P.cW2t + c1 * 128 + kt * 32 + quad * 8);
        }
        const float cw0 = P.cW3[c0], cw1 = P.cW3[c1];
        const float bb0 = P.b2c[c0], bb1 = P.b2c[c1];
#pragma unroll
        for (int mt = 0; mt < 2; mt++) {
            short8 af[4];
#pragma unroll
            for (int kt = 0; kt < 4; kt++)
                af[kt] = *(const short8*)(&mc[(mt * 16 + lrow) * MSTR + kt * 32 + quad * 8]);
            f32x4 a0 = {0.f, 0.f, 0.f, 0.f}, a1 = {0.f, 0.f, 0.f, 0.f};
#pragma unroll
            for (int kt = 0; kt < 4; kt++) {
                a0 = __builtin_amdgcn_mfma_f32_16x16x32_bf16(af[kt], bf0[kt], a0, 0, 0, 0);
                a1 = __builtin_amdgcn_mfma_f32_16x16x32_bf16(af[kt], bf1[kt], a1, 0, 0, 0);
            }
#pragma unroll
            for (int r = 0; r < 4; r++) {
                float v0 = fsilu(a0[r] + bb0);
                float v1 = fsilu(a1[r] + bb1);
                float g = rowSum16(v0 * cw0 + v1 * cw1);
                if (lrow == 0) gpc[wv][mt * 16 + quad * 4 + r] = g;
            }
        }
    }

    // ---- GEMM2e: m2 = silu(m_h @ eW2 + b2); gate partials -> gpe; m2 in regs ----
    float m2s[2][8];
    {
        short8 bf0[4], bf1[4];
#pragma unroll
        for (int kt = 0; kt < 4; kt++) {
            bf0[kt] = *(const short8*)(P.W2t + c0 * 128 + kt * 32 + quad * 8);
            bf1[kt] = *(const short8*)(P.W2t + c1 * 128 + kt * 32 + quad * 8);
        }
        const float aw0 = P.aW[c0], aw1 = P.aW[c1];
        const float bb0 = P.b2e[c0], bb1 = P.b2e[c1];
#pragma unroll
        for (int mt = 0; mt < 2; mt++) {
            short8 af[4];
#pragma unroll
            for (int kt = 0; kt < 4; kt++)
                af[kt] = *(const short8*)(&mh[(mt * 16 + lrow) * MSTR + kt * 32 + quad * 8]);
            f32x4 a0 = {0.f, 0.f, 0.f, 0.f}, a1 = {0.f, 0.f, 0.f, 0.f};
#pragma unroll
            for (int kt = 0; kt < 4; kt++) {
                a0 = __builtin_amdgcn_mfma_f32_16x16x32_bf16(af[kt], bf0[kt], a0, 0, 0, 0);
                a1 = __builtin_amdgcn_mfma_f32_16x16x32_bf16(af[kt], bf1[kt], a1, 0, 0, 0);
            }
#pragma unroll
            for (int r = 0; r < 4; r++) {
                float v0 = fsilu(a0[r] + bb0);
                float v1 = fsilu(a1[r] + bb1);
                m2s[mt][r] = v0; m2s[mt][4 + r] = v1;
                float g = rowSum16(v0 * aw0 + v1 * aw1);
                if (lrow == 0) gpe[wv][mt * 16 + quad * 4 + r] = g;
            }
        }
    }
    __syncthreads();   // B2 (mh/mc reads done -> msg overlay safe; gpc/gpe complete)

    if (t < EPB) {
        sv_l[t]   = gpc[0][t] + gpc[1][t] + gpc[2][t] + gpc[3][t];
        gate_l[t] = fsigm(gpe[0][t] + gpe[1][t] + gpe[2][t] + gpe[3][t] + P.ab[0]);
    }
#pragma unroll
    for (int mt = 0; mt < 2; mt++)
#pragma unroll
        for (int r = 0; r < 4; r++) {
            const int erow = mt * 16 + quad * 4 + r;
            msg[erow * 132 + c0] = m2s[mt][r];
            msg[erow * 132 + c1] = m2s[mt][4 + r];
        }
    __syncthreads();   // B3 (last barrier)

    // ---- segmented reductions (dst-sorted); gate folded into h-scan ----
    // 2-way edge split: threads 0..127 reduce edges 0..15, 128..255 edges 16..31.
    {
        const int col = t & 127;
        const int e0 = (t >> 7) * 16;
        float acc = 0.0f;
        int cur = dstl[e0];
#pragma unroll 4
        for (int e = e0; e < e0 + 16; e++) {
            const int d = dstl[e];
            if (d != cur) {
                atomAddF(&hne[(size_t)cur * 128 + col], acc);
                acc = 0.0f; cur = d;
            }
            acc += msg[e * 132 + col] * gate_l[e];
        }
        atomAddF(&hne[(size_t)cur * 128 + col], acc);
    }
    if (t < 6) {
        const int ax = (t >= 3) ? (t - 3) : t;
        const int e0 = (t >= 3) ? 16 : 0;
        float acc = 0.0f;
        int cur = dstl[e0];
        for (int e = e0; e < e0 + 16; e++) {
            const int d = dstl[e];
            if (d != cur) {
                atomAddF(&xne[cur * 3 + ax], acc);
                acc = 0.0f; cur = d;
            }
            acc += sv_l[e] * xdf[ax][e];
        }
        atomAddF(&xne[cur * 3 + ax], acc);
    }
}

// ---------------------------------------------------------------------------
// Node kernel: reads WS accumulators, writes d_out exactly once per element.
// ---------------------------------------------------------------------------
__global__ __launch_bounds__(256) void node_kernel(
    const float* __restrict__ h_lig, const float* __restrict__ zlig,
    const short* __restrict__ W1t, const float* __restrict__ b1v,
    const short* __restrict__ W2t, const float* __restrict__ b2v,
    const float* __restrict__ x_lig,
    const float* __restrict__ acc_h, const float* __restrict__ acc_x,
    float* __restrict__ h_out, float* __restrict__ x_out)
{
    __shared__ __align__(16) short f_lds[64 * FSTR];
    __shared__ __align__(16) short m_lds[64 * MSTR];
    const int t = threadIdx.x;
    const int nb = blockIdx.x * 64;

    {
        const int e = t >> 2, q = t & 3;
        const int node = nb + e;
        short* frow = &f_lds[e * FSTR + q * 32];
        if (node < 10000) {
            const float zi = frcp(zlig[node]);
            const float4* hp = (const float4*)(h_lig + (size_t)node * 128 + q * 32);
            const float4* np = (const float4*)(acc_h + (size_t)node * 128 + q * 32);
#pragma unroll
            for (int i = 0; i < 8; i++) {
                float4 v = hp[i];
                *(uint2*)(frow + i * 4) = make_uint2(pkbf(v.x, v.y), pkbf(v.z, v.w));
            }
#pragma unroll
            for (int i = 0; i < 8; i++) {
                float4 v = np[i];
                *(uint2*)(frow + 128 + i * 4) =
                    make_uint2(pkbf(v.x * zi, v.y * zi), pkbf(v.z * zi, v.w * zi));
            }
        } else {
            const uint2 zz = make_uint2(0, 0);
#pragma unroll
            for (int i = 0; i < 8; i++) {
                *(uint2*)(frow + i * 4) = zz;
                *(uint2*)(frow + 128 + i * 4) = zz;
            }
        }
    }
    __syncthreads();

    const int ln = t & 63, wv = t >> 6;
    const int lrow = ln & 15, quad = ln >> 4;
    const int c0 = wv * 32 + lrow, c1 = c0 + 16;

    {
        short8 bf0[8], bf1[8];
#pragma unroll
        for (int kt = 0; kt < 8; kt++) {
            bf0[kt] = *(const short8*)(W1t + c0 * 256 + kt * 32 + quad * 8);
            bf1[kt] = *(const short8*)(W1t + c1 * 256 + kt * 32 + quad * 8);
        }
        const float bb0 = b1v[c0], bb1 = b1v[c1];
#pragma unroll
        for (int mt = 0; mt < 4; mt++) {
            short8 af[8];
#pragma unroll
            for (int kt = 0; kt < 8; kt++)
                af[kt] = *(const short8*)(&f_lds[(mt * 16 + lrow) * FSTR + kt * 32 + quad * 8]);
            f32x4 a0 = {0.f, 0.f, 0.f, 0.f}, a1 = {0.f, 0.f, 0.f, 0.f};
#pragma unroll
            for (int kt = 0; kt < 8; kt++) {
                a0 = __builtin_amdgcn_mfma_f32_16x16x32_bf16(af[kt], bf0[kt], a0, 0, 0, 0);
                a1 = __builtin_amdgcn_mfma_f32_16x16x32_bf16(af[kt], bf1[kt], a1, 0, 0, 0);
            }
#pragma unroll
            for (int r = 0; r < 4; r++) {
                const int erow = mt * 16 + quad * 4 + r;
                m_lds[erow * MSTR + c0] = (short)f2bf(fsilu(a0[r] + bb0));
                m_lds[erow * MSTR + c1] = (short)f2bf(fsilu(a1[r] + bb1));
            }
        }
    }
    __syncthreads();

    {
        short8 bf0[4], bf1[4];
#pragma unroll
        for (int kt = 0; kt < 4; kt++) {
            bf0[kt] = *(const short8*)(W2t + c0 * 128 + kt * 32 + quad * 8);
            bf1[kt] = *(const short8*)(W2t + c1 * 128 + kt * 32 + quad * 8);
        }
        const float bb0 = b2v[c0], bb1 = b2v[c1];
#pragma unroll
        for (int mt = 0; mt < 4; mt++) {
            short8 af[4];
#pragma unroll
            for (int kt = 0; kt < 4; kt++)
                af[kt] = *(const short8*)(&m_lds[(mt * 16 + lrow) * MSTR + kt * 32 + quad * 8]);
            f32x4 a0 = {0.f, 0.f, 0.f, 0.f}, a1 = {0.f, 0.f, 0.f, 0.f};
#pragma unroll
            for (int kt = 0; kt < 4; kt++) {
                a0 = __builtin_amdgcn_mfma_f32_16x16x32_bf16(af[kt], bf0[kt], a0, 0, 0, 0);
                a1 = __builtin_amdgcn_mfma_f32_16x16x32_bf16(af[kt], bf1[kt], a1, 0, 0, 0);
            }
#pragma unroll
            for (int r = 0; r < 4; r++) {
                const int node = nb + mt * 16 + quad * 4 + r;
                if (node < 10000) {
                    h_out[(size_t)node * 128 + c0] = a0[r] + bb0 + h_lig[(size_t)node * 128 + c0];
                    h_out[(size_t)node * 128 + c1] = a1[r] + bb1 + h_lig[(size_t)node * 128 + c1];
                }
            }
        }
    }
    if (t < 64) {
        const int node = nb + t;
        if (node < 10000) {
            const float zi = frcp(zlig[node]);
#pragma unroll
            for (int i = 0; i < 3; i++)
                x_out[node * 3 + i] = x_lig[node * 3 + i] + acc_x[node * 3 + i] * zi;
        }
    }
}

extern "C" void kernel_launch(void* const* d_in, const int* in_sizes, int n_in,
                              void* d_out, int out_size, void* d_ws, size_t ws_size,
                              hipStream_t stream)
{
    (void)in_sizes; (void)n_in; (void)ws_size; (void)out_size;
    const float* h_lig  = (const float*)d_in[0];
    const float* h_kp   = (const float*)d_in[1];
    const float* x_lig  = (const float*)d_in[2];
    const float* x_kp   = (const float*)d_in[3];
    const float* z_lig  = (const float*)d_in[4];
    const float* ll_eW1 = (const float*)d_in[5];
    const float* ll_eb1 = (const float*)d_in[6];
    const float* ll_eW2 = (const float*)d_in[7];
    const float* ll_eb2 = (const float*)d_in[8];
    const float* ll_aW  = (const float*)d_in[9];
    const float* ll_ab  = (const float*)d_in[10];
    const float* ll_cW1 = (const float*)d_in[11];
    const float* ll_cb1 = (const float*)d_in[12];
    const float* ll_cW2 = (const float*)d_in[13];
    const float* ll_cb2 = (const float*)d_in[14];
    const float* ll_cW3 = (const float*)d_in[15];
    const float* kl_eW1 = (const float*)d_in[16];
    const float* kl_eb1 = (const float*)d_in[17];
    const float* kl_eW2 = (const float*)d_in[18];
    const float* kl_eb2 = (const float*)d_in[19];
    const float* kl_aW  = (const float*)d_in[20];
    const float* kl_ab  = (const float*)d_in[21];
    const float* kl_cW1 = (const float*)d_in[22];
    const float* kl_cb1 = (const float*)d_in[23];
    const float* kl_cW2 = (const float*)d_in[24];
    const float* kl_cb2 = (const float*)d_in[25];
    const float* kl_cW3 = (const float*)d_in[26];
    const float* n_W1   = (const float*)d_in[27];
    const float* n_b1   = (const float*)d_in[28];
    const float* n_W2   = (const float*)d_in[29];
    const float* n_b2   = (const float*)d_in[30];
    const int* ll_src = (const int*)d_in[31];
    const int* ll_dst = (const int*)d_in[32];
    const int* kl_src = (const int*)d_in[33];
    const int* kl_dst = (const int*)d_in[34];

    float* h_out = (float*)d_out;            // [10000,128]
    float* x_out = h_out + 1280000;          // [10000,3]

    // ws layout (bytes) — ~26.1 MB; accumulators live in WS (d_out write-once)
    char* wsc = (char*)d_ws;
    short* wsb    = (short*)wsc;                 //       0: weights (491,520 B)
    short* P_ll_s = (short*)(wsc +   491520);    // 5,120,000 B  [10000][256]
    short* P_ll_d = (short*)(wsc +  5611520);    // 5,120,000 B
    short* P_kl_s = (short*)(wsc + 10731520);    // 1,024,000 B  [2000][256]
    short* P_kl_d = (short*)(wsc + 11755520);    // 5,120,000 B
    int2* ll_spk  = (int2*)(wsc + 16875520);     // 2,560,000 B  packed (src,dst)
    int2* kl_spk  = (int2*)(wsc + 19435520);     // 1,280,000 B
    int* hist     = (int*)(wsc + 20715520);      //    80,000 B (20000 ints)
    int* cursor   = (int*)(wsc + 20795520);      //    80,000 B
    float* hne    = (float*)(wsc + 20875520);    // 5,120,000 B  [10000][128]
    float* xne    = (float*)(wsc + 25995520);    //   120,000 B  [10000][3] -> end 26,115,520

    (void)hipMemsetAsync(hist, 0, 80000, stream);

    // A. weight transpose + histogram + hne/xne zero-fill
    {
        PrepArgs pa;
        pa.src[0] = ll_eW1; pa.src[1] = ll_eW2; pa.src[2] = ll_cW1; pa.src[3] = ll_cW2;
        pa.src[4] = kl_eW1; pa.src[5] = kl_eW2; pa.src[6] = kl_cW1; pa.src[7] = kl_cW2;
        pa.src[8] = n_W1;   pa.src[9] = n_W2;
        prep_hist_kernel<<<4115, 256, 0, stream>>>(pa, wsb, ll_dst, kl_dst, hist, hne);
    }
    // B. scan (2 blocks) overlapped with PAIRED projection GEMMs (628 blocks)
    {
        BArgs ba;
        ba.hist = hist; ba.cursor = cursor;
        ba.p[0] = { h_lig, wsb + 0,     wsb + 49152,  P_ll_s, ll_eb1, ll_cb1, 10000, 0, 0 };
        ba.p[1] = { h_lig, wsb + 0,     wsb + 49152,  P_ll_d, ll_eb1, ll_cb1, 10000, 4, 1 };
        ba.p[2] = { h_kp,  wsb + 98304, wsb + 147456, P_kl_s, kl_eb1, kl_cb1,  2000, 0, 0 };
        ba.p[3] = { h_lig, wsb + 98304, wsb + 147456, P_kl_d, kl_eb1, kl_cb1, 10000, 4, 1 };
        scan_proj_kernel<<<2 + 4 * 157, 256, 0, stream>>>(ba);
    }
    // C. scatter
    {
        SArgs sa;
        sa.lls = ll_src; sa.lld = ll_dst; sa.kls = kl_src; sa.kld = kl_dst;
        sa.cursor = cursor;
        sa.ll_spk = ll_spk; sa.kl_spk = kl_spk;
        scatter_kernel<<<1875, 256, 0, stream>>>(sa);
    }
    // D. edges (ll + kl in one launch), EPB=32, XCD-swizzled
    {
        EdgePair ep;
        ep.split = 10000;
        ep.s[0] = { P_ll_s, P_ll_d, x_lig, x_lig, ll_spk,
                    ll_eW1 + 256 * 128, ll_cW1 + 256 * 128,
                    wsb + 32768, wsb + 81920, ll_eb2, ll_cb2,
                    ll_aW, ll_ab, ll_cW3 };
        ep.s[1] = { P_kl_s, P_kl_d, x_kp, x_lig, kl_spk,
                    kl_eW1 + 256 * 128, kl_cW1 + 256 * 128,
                    wsb + 131072, wsb + 180224, kl_eb2, kl_cb2,
                    kl_aW, kl_ab, kl_cW3 };
        edge_kernel<<<15000, 256, 0, stream>>>(ep, hne, xne);
    }
    // E. node MLP -> final outputs into d_out (write-once)
    node_kernel<<<157, 256, 0, stream>>>(
        h_lig, z_lig, wsb + 196608, n_b1, wsb + 229376, n_b2,
        x_lig, hne, xne, h_out, x_out);
}